// Round 3
// baseline (21829.584 us; speedup 1.0000x reference)
//
#include <hip/hip_runtime.h>

#define T_STEPS 512
#define BATCH   256
#define DIN     256
#define DHID    256
#define DCOMB   512
#define BBLK    16       // batch rows per group
#define NGRP    16       // batch groups
#define NMEM    8        // members per group: 4 gates x 2 halves, n-slice 128
#define NWG     (NGRP * NMEM)   // 128 workgroups
#define NTHREADS 256     // 4 waves
#define KT      16       // K tiles of 32 over DCOMB
#define NT_W    2        // n-tiles (of 16) per wave: 8 ntiles / 4 waves

typedef short bf16_t;
typedef __attribute__((ext_vector_type(8))) short short8;
typedef __attribute__((ext_vector_type(4))) float f32x4;

#define APAD 8
#define AROW (DCOMB + APAD)   // 520 bf16, 1040 B row stride
#define THR  132              // TH row stride (floats): 128 + 4 pad

// -------- workspace layout (bytes) --------
#define WS_WP     0                         // 1 MB packed W (bf16, B-frag order)
#define WS_BIAS   (1u << 20)                // 4 KB
#define WS_TEMPS  ((1u << 20) + 4096u)      // 16 B
#define WS_CUM    (2u << 20)                // 1 MB: [16 gg][8 m][16 b][128] f32
#define WS_SEGTOT (3u << 20)                // 4 KB: [16 gg][4 g][16 b] f32
#define WS_HG     ((3u << 20) + 65536u)     // 128 KB: [16 gg][16 b][256] bf16
#define WS_CTR    ((3u << 20) + 65536u + 131072u)  // 2 KB: 512 uints

__device__ inline short f2bf(float f) {
  union { float f; unsigned u; } v; v.f = f;
  unsigned r = (v.u + 0x7FFFu + ((v.u >> 16) & 1u)) >> 16;
  return (short)r;
}

__device__ inline float fast_sigmoid(float x) {
  return 1.f / (1.f + __expf(-x));
}

__device__ inline float fast_tanh(float x) {
  float ax = fabsf(x);
  float e = __expf(2.f * ax);             // inf-safe: 1 - 2/inf = 1
  float r = 1.f - 2.f / (e + 1.f);
  return copysignf(r, x);
}

// Pack W into MFMA-B-fragment order: elem[((nt*16+kt)*64+lane)*8 + j] =
// bf16( W[gate][nrow][k] ), n = nt*16+(lane&15), gate=n>>8, nrow=n&255,
// k = kt*32 + (lane>>4)*8 + j.  Also bias[1024], temps[4], and zero the
// group-barrier counters (stream-ordered before the main kernel).
__global__ __launch_bounds__(256) void pack_w(
    const float* __restrict__ Wf, const float* __restrict__ Wi,
    const float* __restrict__ Wg, const float* __restrict__ Wo,
    const float* __restrict__ bf_, const float* __restrict__ bi_,
    const float* __restrict__ bg_, const float* __restrict__ bo_,
    const float* __restrict__ tf_, const float* __restrict__ ti_,
    const float* __restrict__ tg_, const float* __restrict__ to_,
    bf16_t* __restrict__ Wp, float* __restrict__ bias,
    float* __restrict__ temps, unsigned* __restrict__ ctr)
{
  int tid = blockIdx.x * 256 + threadIdx.x;   // 65536 threads
  int lane = tid & 63;
  int kt = (tid >> 6) & 15;
  int nt = tid >> 10;
  int n = nt * 16 + (lane & 15);
  int gate = n >> 8, nrow = n & 255;
  int k = kt * 32 + (lane >> 4) * 8;
  const float* W = gate == 0 ? Wf : gate == 1 ? Wi : gate == 2 ? Wg : Wo;
  const float* src = W + nrow * DCOMB + k;
  short8 d;
#pragma unroll
  for (int j = 0; j < 8; ++j) d[j] = f2bf(src[j]);
  *(short8*)(Wp + (size_t)tid * 8) = d;

  if (tid < 1024) {
    int g2 = tid >> 8;
    const float* bs = g2 == 0 ? bf_ : g2 == 1 ? bi_ : g2 == 2 ? bg_ : bo_;
    bias[tid] = bs[tid & 255];
  }
  if (tid < 4) {
    const float* ts = tid == 0 ? tf_ : tid == 1 ? ti_ : tid == 2 ? tg_ : to_;
    temps[tid] = ts[0];
  }
  if (tid < 512) ctr[tid] = 0;
}

// 8-WG group barrier: monotonic counter, device-scope atomics.
__device__ inline void grp_barrier(unsigned* c, unsigned target) {
  __syncthreads();
  __threadfence();                 // publish this WG's global writes
  if (threadIdx.x == 0) {
    __hip_atomic_fetch_add(c, 1u, __ATOMIC_RELEASE, __HIP_MEMORY_SCOPE_AGENT);
    while (__hip_atomic_load(c, __ATOMIC_ACQUIRE, __HIP_MEMORY_SCOPE_AGENT) < target)
      __builtin_amdgcn_s_sleep(1);
  }
  __threadfence();                 // acquire: invalidate caches before reads
  __syncthreads();
}

__global__ __launch_bounds__(NTHREADS, 1) void qlstm_rec(
    const float* __restrict__ x,       // [T, B, DIN]
    const bf16_t* __restrict__ Wp,     // packed bf16 W (B-frag order)
    const float* __restrict__ bias,    // [1024]
    const float* __restrict__ temps,   // [4]
    float* __restrict__ cum,           // [16][8][16][128]
    float* __restrict__ segtot,        // [16][4][16]
    bf16_t* __restrict__ hG,           // [16][16][256]
    unsigned* __restrict__ ctr,        // barriers
    float* __restrict__ out)           // [T*B*DHID + 2*B*DHID]
{
  __shared__ bf16_t A[BBLK * AROW];    // comb tile (x|h) bf16
  __shared__ float  TH[BBLK * THR];    // cos(theta) for this WG's 128-n slice

  const int tid  = threadIdx.x;
  const int wave = tid >> 6, lane = tid & 63;
  const int bid  = blockIdx.x;
  const int gg   = bid & 15;           // batch group
  const int m    = bid >> 4;           // member: n-slice [m*128, m*128+128)
  const int b0   = gg * BBLK;

  unsigned* ctrA = ctr + gg * 16;
  unsigned* ctrB = ctr + 256 + gg * 16;

  // ---- W slice -> VGPRs (resident for all 512 steps) ----
  short8 wv[NT_W][KT];
#pragma unroll
  for (int i = 0; i < NT_W; ++i)
#pragma unroll
    for (int kt = 0; kt < KT; ++kt)
      wv[i][kt] = *(const short8*)(Wp +
          ((((size_t)(m * 8 + wave * NT_W + i) * KT + kt) * 64 + lane) * 8));

  float bn[NT_W];
#pragma unroll
  for (int i = 0; i < NT_W; ++i)
    bn[i] = bias[m * 128 + (wave * NT_W + i) * 16 + (lane & 15)];

  const float it0 = 1.f / temps[0], it1 = 1.f / temps[1];
  const float it2 = 1.f / temps[2], it3 = 1.f / temps[3];

  // MFMA A-frag coords: lane holds A[lane&15][(lane>>4)*8 + j]
  const int arow  = lane & 15;
  const int acol0 = (lane >> 4) * 8;

  // cumprod mapping: thread (cb, cs): row cb, 8-elem segment cs
  const int cb = tid >> 4, cs = tid & 15;

  // cell-update mapping: kk-range [m*32, m*32+32); thread does rows bu, bu+8
  const int kkr  = tid & 31;
  const int bu   = tid >> 5;           // 0..7
  const int hfu  = m >> 2;             // which gate-half covers our kk range
  const int klb  = (m & 3) * 32;       // kl base within that half

  float creg0 = 0.f, creg1 = 0.f;      // cell state for (bu, kkr), (bu+8, kkr)

  for (int t = 0; t < T_STEPS; ++t) {
    // ---- 1. build A(t) = [x(t) | h(t-1)] ----
    {
      int b = tid >> 4, c0 = (tid & 15) * 16;
      const float4* xs = (const float4*)(x + ((size_t)t * BATCH + b0 + b) * DIN + c0);
      float4 v0 = xs[0], v1 = xs[1], v2 = xs[2], v3 = xs[3];
      short8 d0, d1;
      d0[0] = f2bf(v0.x); d0[1] = f2bf(v0.y); d0[2] = f2bf(v0.z); d0[3] = f2bf(v0.w);
      d0[4] = f2bf(v1.x); d0[5] = f2bf(v1.y); d0[6] = f2bf(v1.z); d0[7] = f2bf(v1.w);
      d1[0] = f2bf(v2.x); d1[1] = f2bf(v2.y); d1[2] = f2bf(v2.z); d1[3] = f2bf(v2.w);
      d1[4] = f2bf(v3.x); d1[5] = f2bf(v3.y); d1[6] = f2bf(v3.z); d1[7] = f2bf(v3.w);
      *(short8*)&A[b * AROW + c0]     = d0;
      *(short8*)&A[b * AROW + c0 + 8] = d1;
      short8 h0, h1;
      if (t == 0) {
        h0 = (short8){0,0,0,0,0,0,0,0};
        h1 = h0;
      } else {
        const short8* hs = (const short8*)(hG + ((size_t)(gg * 16 + b)) * 256 + c0);
        h0 = hs[0]; h1 = hs[1];
      }
      *(short8*)&A[b * AROW + DIN + c0]     = h0;
      *(short8*)&A[b * AROW + DIN + c0 + 8] = h1;
    }
    __syncthreads();

    // ---- 2. GEMM: theta[16 x 128-slice] = A @ W^T (W in VGPRs) ----
    f32x4 acc[NT_W];
#pragma unroll
    for (int i = 0; i < NT_W; ++i) acc[i] = (f32x4){0.f, 0.f, 0.f, 0.f};
#pragma unroll
    for (int kt = 0; kt < KT; ++kt) {
      short8 a = *(const short8*)&A[arow * AROW + kt * 32 + acol0];
#pragma unroll
      for (int i = 0; i < NT_W; ++i)
        acc[i] = __builtin_amdgcn_mfma_f32_16x16x32_bf16(a, wv[i][kt], acc[i], 0, 0, 0);
    }

    // ---- 3. cos(theta+bias) -> TH (C/D: col=lane&15, row=(lane>>4)*4+r) ----
#pragma unroll
    for (int i = 0; i < NT_W; ++i) {
      int nl = (wave * NT_W + i) * 16 + (lane & 15);
      int brow = (lane >> 4) * 4;
#pragma unroll
      for (int r = 0; r < 4; ++r)
        TH[(brow + r) * THR + nl] = __cosf(acc[i][r] + bn[i]);
    }
    __syncthreads();

    // ---- 4. local cumprod over the 128-n slice; write to global ----
    {
      f32x4 t0 = *(const f32x4*)&TH[cb * THR + cs * 8];
      f32x4 t1 = *(const f32x4*)&TH[cb * THR + cs * 8 + 4];
      float p = t0[0] * t0[1] * t0[2] * t0[3] * t1[0] * t1[1] * t1[2] * t1[3];
      // inclusive scan of segment products across 16 lanes (width 16)
      float incl = p;
#pragma unroll
      for (int d = 1; d < 16; d <<= 1) {
        float o = __shfl_up(incl, d, 16);
        if ((lane & 15) >= d) incl *= o;
      }
      float pre = __shfl_up(incl, 1, 16);
      if ((lane & 15) == 0) pre = 1.f;
      float c0v = pre * t0[0];
      float c1v = c0v * t0[1];
      float c2v = c1v * t0[2];
      float c3v = c2v * t0[3];
      float c4v = c3v * t1[0];
      float c5v = c4v * t1[1];
      float c6v = c5v * t1[2];
      float c7v = c6v * t1[3];
      float4* cw = (float4*)(cum + (((size_t)(gg * 8 + m) * 16 + cb) * 128 + cs * 8));
      cw[0] = make_float4(c0v, c1v, c2v, c3v);
      cw[1] = make_float4(c4v, c5v, c6v, c7v);
      if ((m & 1) == 0 && cs == 15)
        segtot[(gg * 4 + (m >> 1)) * 16 + cb] = c7v;   // total of first half
    }
    grp_barrier(ctrA, 8u * (t + 1));   // cum/segtot ready group-wide

    // ---- 5. cell update for kk in [m*32, m*32+32) ----
    {
      const size_t cbase = (size_t)gg * 8 * 16 * 128;
#pragma unroll
      for (int j = 0; j < 2; ++j) {
        int b = bu + 8 * j;
        size_t ro = (size_t)b * 128 + klb + kkr;
        float cf = cum[cbase + ((0 * 2 + hfu) * 16) * 128 + ro];
        float ci = cum[cbase + ((1 * 2 + hfu) * 16) * 128 + ro];
        float cg = cum[cbase + ((2 * 2 + hfu) * 16) * 128 + ro];
        float co = cum[cbase + ((3 * 2 + hfu) * 16) * 128 + ro];
        if (hfu) {
          cf *= segtot[(gg * 4 + 0) * 16 + b];
          ci *= segtot[(gg * 4 + 1) * 16 + b];
          cg *= segtot[(gg * 4 + 2) * 16 + b];
          co *= segtot[(gg * 4 + 3) * 16 + b];
        }
        float fv = fast_sigmoid(cf * it0);
        float iv = fast_sigmoid(ci * it1);
        float gv = fast_tanh(cg * it2);
        float ov = fast_sigmoid(co * it3);
        float& cr = j ? creg1 : creg0;
        float c = fv * cr + iv * gv;
        cr = c;
        float h = ov * fast_tanh(c);
        int kk = m * 32 + kkr;
        out[((size_t)t * BATCH + b0 + b) * DHID + kk] = h;
        hG[((size_t)(gg * 16 + b)) * 256 + kk] = f2bf(h);
        if (t == T_STEPS - 1) {
          out[((size_t)T_STEPS * BATCH + b0 + b) * DHID + kk] = h;           // hx
          out[((size_t)T_STEPS * BATCH + BATCH + b0 + b) * DHID + kk] = c;   // cx
        }
      }
    }
    grp_barrier(ctrB, 8u * (t + 1));   // h(t) ready group-wide
  }
}

extern "C" void kernel_launch(void* const* d_in, const int* in_sizes, int n_in,
                              void* d_out, int out_size, void* d_ws, size_t ws_size,
                              hipStream_t stream) {
  const float* x   = (const float*)d_in[0];
  const float* Wf  = (const float*)d_in[1];
  const float* bf_ = (const float*)d_in[2];
  const float* tf_ = (const float*)d_in[3];
  const float* Wi  = (const float*)d_in[4];
  const float* bi_ = (const float*)d_in[5];
  const float* ti_ = (const float*)d_in[6];
  const float* Wg  = (const float*)d_in[7];
  const float* bg_ = (const float*)d_in[8];
  const float* tg_ = (const float*)d_in[9];
  const float* Wo  = (const float*)d_in[10];
  const float* bo_ = (const float*)d_in[11];
  const float* to_ = (const float*)d_in[12];

  char* ws = (char*)d_ws;
  bf16_t*   Wp     = (bf16_t*)(ws + WS_WP);
  float*    bias   = (float*)(ws + WS_BIAS);
  float*    temps  = (float*)(ws + WS_TEMPS);
  float*    cum    = (float*)(ws + WS_CUM);
  float*    segtot = (float*)(ws + WS_SEGTOT);
  bf16_t*   hG     = (bf16_t*)(ws + WS_HG);
  unsigned* ctr    = (unsigned*)(ws + WS_CTR);

  hipLaunchKernelGGL(pack_w, dim3(256), dim3(256), 0, stream,
                     Wf, Wi, Wg, Wo, bf_, bi_, bg_, bo_, tf_, ti_, tg_, to_,
                     Wp, bias, temps, ctr);

  hipLaunchKernelGGL(qlstm_rec, dim3(NWG), dim3(NTHREADS), 0, stream,
                     x, Wp, bias, temps, cum, segtot, hG, ctr, (float*)d_out);
}

// Round 4
// 7319.883 us; speedup vs baseline: 2.9822x; 2.9822x over previous
//
#include <hip/hip_runtime.h>

#define T_STEPS 512
#define BATCH   256
#define DIN     256
#define DHID    256
#define NWG     16
#define BBLK    16

typedef short bf16_t;
typedef __attribute__((ext_vector_type(4))) short short4v;
typedef __attribute__((ext_vector_type(8))) short short8;
typedef __attribute__((ext_vector_type(4))) float f32x4;
typedef unsigned int uint;

// ---- REC LDS layout (bytes) ----
#define WL_NT_V   13                    // ntiles (of 16 n) per gate in VGPR/AGPR
#define WL_NT_LDS 3                     // ntiles per gate in LDS (i = 13,14,15)
#define OFF_WL  0
#define SZ_WL   (4 * WL_NT_LDS * 8 * 64 * 16)   // 98304
#define OFF_A   (OFF_WL + SZ_WL)                // A[16][256] bf16, XOR-swizzled
#define SZ_A    (16 * 512)                      // 8192
#define OFF_TH  (OFF_A + SZ_A)
#define THSTR   264                             // bf16 elems per TH row
#define SZ_TH   (64 * THSTR * 2)                // 33792
#define OFF_C   (OFF_TH + SZ_TH)
#define CSTR    264                             // f32 per C row
#define SZ_C    (16 * CSTR * 4)                 // 16896
#define LDS_REC (OFF_C + SZ_C)                  // 157184

// ---- workspace layout (bytes) ----
#define WS_WHP   0u                        // 512 KB Wh packed (B-frag order)
#define WS_WXP   (512u << 10)              // 512 KB Wx packed
#define WS_BIAS  (1u << 20)                // 4 KB
#define WS_TMP   ((1u << 20) + 4096u)      // 16 B
#define WS_HG    ((1u << 20) + 8192u)      // 128 KB  h state bf16 [256][256]
#define WS_CG    ((1u << 20) + 8192u + 131072u)  // 256 KB c state f32
#define WS_THX   (2u << 20)                // CH*512 KB theta_x chunk

__device__ inline short f2bf(float f) {
  union { float f; uint u; } v; v.f = f;
  uint r = (v.u + 0x7FFFu + ((v.u >> 16) & 1u)) >> 16;
  return (short)r;
}
__device__ inline float bf2f(short s) {
  union { float f; uint u; } v; v.u = ((uint)(unsigned short)s) << 16;
  return v.f;
}
__device__ inline float u2f(uint u) {
  union { float f; uint u; } v; v.u = u; return v.f;
}
__device__ inline float fast_sigmoid(float x) { return 1.f / (1.f + __expf(-x)); }
__device__ inline float fast_tanh(float x) {
  float ax = fabsf(x);
  float e = __expf(2.f * ax);
  float r = 1.f - 2.f / (e + 1.f);
  return copysignf(r, x);
}

// Pack Wx (k<256) and Wh (k>=256) into MFMA B-frag order.
// frag(nt, kt): elem[((nt*8+kt)*64+lane)*8 + j] = W[n][k],
//   n = nt*16 + (lane&15), k = kbase + kt*32 + (lane>>4)*8 + j.
__global__ __launch_bounds__(256) void pack_w(
    const float* __restrict__ Wf, const float* __restrict__ Wi,
    const float* __restrict__ Wg, const float* __restrict__ Wo,
    const float* __restrict__ bf_, const float* __restrict__ bi_,
    const float* __restrict__ bg_, const float* __restrict__ bo_,
    const float* __restrict__ tf_, const float* __restrict__ ti_,
    const float* __restrict__ tg_, const float* __restrict__ to_,
    bf16_t* __restrict__ Wxp, bf16_t* __restrict__ Whp,
    float* __restrict__ bias, float* __restrict__ temps)
{
  int tid = blockIdx.x * 256 + threadIdx.x;   // 65536 threads
  int half = tid >> 15;                        // 0: Wx, 1: Wh
  int idx = tid & 32767;
  int nt = idx >> 9;                           // 0..63
  int kt = (idx >> 6) & 7;
  int lane = idx & 63;
  int n = nt * 16 + (lane & 15);
  int gate = n >> 8, nrow = n & 255;
  int k = (half ? 256 : 0) + kt * 32 + (lane >> 4) * 8;
  const float* W = gate == 0 ? Wf : gate == 1 ? Wi : gate == 2 ? Wg : Wo;
  const float* src = W + (size_t)nrow * 512 + k;
  short8 d;
#pragma unroll
  for (int j = 0; j < 8; ++j) d[j] = f2bf(src[j]);
  bf16_t* dst = half ? Whp : Wxp;
  *(short8*)(dst + (size_t)idx * 8) = d;

  if (tid < 1024) {
    int g2 = tid >> 8;
    const float* bs = g2 == 0 ? bf_ : g2 == 1 ? bi_ : g2 == 2 ? bg_ : bo_;
    bias[tid] = bs[tid & 255];
  }
  if (tid < 4) {
    const float* ts = tid == 0 ? tf_ : tid == 1 ? ti_ : tid == 2 ? tg_ : to_;
    temps[tid] = ts[0];
  }
}

// theta_x GEMM: thx[trel][gg][gate][i][lane] (short4 = acc r0..r3, bf16)
//   = x_chunk[m][0:256] @ Wx.T + bias,  m = trel*256 + gg*16 + b.
__global__ __launch_bounds__(256, 1) void gemm_thx(
    const float* __restrict__ x,        // chunk slice [CH*256, 256]
    const bf16_t* __restrict__ Wxp,
    const float* __restrict__ bias,
    bf16_t* __restrict__ thx)
{
  __shared__ bf16_t Ax[64 * 256];       // XOR-swizzled, 512 B row stride
  const int tid = threadIdx.x;
  const int wave = tid >> 6, lane = tid & 63;
  const int mb = blockIdx.x * 64;

  // stage x -> bf16 LDS (coalesced float4 reads)
#pragma unroll
  for (int rep = 0; rep < 16; ++rep) {
    int idx = tid + rep * 256;          // float4 slot
    int row = idx >> 6, c4f = (idx & 63) * 4;
    float4 v = *(const float4*)(x + (size_t)(mb + row) * 256 + c4f);
    short4v d;
    d[0] = f2bf(v.x); d[1] = f2bf(v.y); d[2] = f2bf(v.z); d[3] = f2bf(v.w);
    *(short4v*)((char*)Ax + row * 512 + ((c4f * 2) ^ ((row & 7) << 4))) = d;
  }
  __syncthreads();

  // cache all A-frags in regs: af[mf][kt]
  short8 af[4][8];
#pragma unroll
  for (int mf = 0; mf < 4; ++mf)
#pragma unroll
    for (int kt = 0; kt < 8; ++kt) {
      int row = mf * 16 + (lane & 15);
      int kb = kt * 64 + (lane >> 4) * 16;
      af[mf][kt] = *(const short8*)((char*)Ax + row * 512 + (kb ^ ((row & 7) << 4)));
    }

  uint2* thx2 = (uint2*)thx;
#pragma unroll 1
  for (int i = 0; i < 16; ++i) {
    short8 wfr[8];
#pragma unroll
    for (int kt = 0; kt < 8; ++kt)
      wfr[kt] = *(const short8*)(Wxp + ((((size_t)(wave * 16 + i)) * 8 + kt) * 64 + lane) * 8);
    float bv = bias[wave * 256 + i * 16 + (lane & 15)];
    f32x4 ac[4];
#pragma unroll
    for (int mf = 0; mf < 4; ++mf) ac[mf] = (f32x4){0.f, 0.f, 0.f, 0.f};
#pragma unroll
    for (int kt = 0; kt < 8; ++kt)
#pragma unroll
      for (int mf = 0; mf < 4; ++mf)
        ac[mf] = __builtin_amdgcn_mfma_f32_16x16x32_bf16(af[mf][kt], wfr[kt], ac[mf], 0, 0, 0);
#pragma unroll
    for (int mf = 0; mf < 4; ++mf) {
      int mrow = mb + mf * 16;
      int trel = mrow >> 8, gg = (mrow >> 4) & 15;
      size_t di = ((((size_t)trel * 16 + gg) * 4 + wave) * 16 + i) * 64 + lane;
      uint2 pk;
      pk.x = (uint)(unsigned short)f2bf(ac[mf][0] + bv) |
             ((uint)(unsigned short)f2bf(ac[mf][1] + bv) << 16);
      pk.y = (uint)(unsigned short)f2bf(ac[mf][2] + bv) |
             ((uint)(unsigned short)f2bf(ac[mf][3] + bv) << 16);
      thx2[di] = pk;
    }
  }
}

// Recurrent kernel: 16 WGs x 256 thr (4 waves, 1/SIMD). Wave = gate.
// Wh resident: 13 ntiles in VGPR/AGPR + 3 in LDS. Zero W traffic per step.
__global__ __launch_bounds__(256, 1) void qlstm_rec(
    const bf16_t* __restrict__ thx,
    const bf16_t* __restrict__ Whp,
    const float* __restrict__ temps,
    bf16_t* __restrict__ hG, float* __restrict__ cG,
    float* __restrict__ out,
    int t0, int nsteps)
{
  extern __shared__ char smem[];
  bf16_t* WL = (bf16_t*)(smem + OFF_WL);
  char*   Ab = smem + OFF_A;
  bf16_t* TH = (bf16_t*)(smem + OFF_TH);
  float*  C  = (float*)(smem + OFF_C);

  const int tid = threadIdx.x;
  const int g = tid >> 6, lane = tid & 63;
  const int lg = lane >> 4, c = lane & 15;
  const int gg = blockIdx.x, b0 = gg * BBLK;

  // ---- Wh -> VGPR/AGPR frags (resident across all steps) + LDS tail ----
  short8 wv[WL_NT_V][8];
#pragma unroll
  for (int i = 0; i < WL_NT_V; ++i)
#pragma unroll
    for (int kt = 0; kt < 8; ++kt)
      wv[i][kt] = *(const short8*)(Whp + ((((size_t)(g * 16 + i)) * 8 + kt) * 64 + lane) * 8);
#pragma unroll
  for (int i = 0; i < WL_NT_LDS; ++i)
#pragma unroll
    for (int kt = 0; kt < 8; ++kt)
      *(short8*)(WL + (((g * WL_NT_LDS + i) * 8 + kt) * 64 + lane) * 8) =
          *(const short8*)(Whp + ((((size_t)(g * 16 + 13 + i)) * 8 + kt) * 64 + lane) * 8);

  // ---- init A (h) and C (c) ----
  for (int rep = 0; rep < 16; ++rep) {
    int idx = tid + rep * 256;
    int b = idx >> 8, kk = idx & 255;
    bf16_t hv = 0; float cv = 0.f;
    if (t0 != 0) {
      hv = hG[(size_t)(b0 + b) * 256 + kk];
      cv = cG[(size_t)(b0 + b) * 256 + kk];
    }
    *(bf16_t*)(Ab + b * 512 + ((kk * 2) ^ ((b & 7) << 4))) = hv;
    C[b * CSTR + kk] = cv;
  }
  __syncthreads();

  const float invt = 1.f / temps[g];
  const uint2* thx2 = (const uint2*)thx;

  // prologue theta_x loads (step 0)
  uint2 tx[16];
  {
    const uint2* tb = thx2 + (((size_t)0 * 16 + gg) * 4 + g) * 1024 + lane;
#pragma unroll
    for (int i = 0; i < 16; ++i) tx[i] = tb[i * 64];
  }

#pragma unroll 1
  for (int ts = 0; ts < nsteps; ++ts) {
    const int t = t0 + ts;

    // ---- GEMM theta = theta_x + h @ Wh.T, per gate-wave; stage cos -> TH --
#pragma unroll
    for (int grp = 0; grp < 4; ++grp) {
      f32x4 ac[4];
#pragma unroll
      for (int q = 0; q < 4; ++q) {
        uint lo = tx[grp * 4 + q].x, hi = tx[grp * 4 + q].y;
        ac[q][0] = u2f(lo << 16);
        ac[q][1] = u2f(lo & 0xffff0000u);
        ac[q][2] = u2f(hi << 16);
        ac[q][3] = u2f(hi & 0xffff0000u);
      }
#pragma unroll
      for (int kt = 0; kt < 8; ++kt) {
        short8 a = *(const short8*)(Ab + c * 512 + ((kt * 64 + lg * 16) ^ ((c & 7) << 4)));
#pragma unroll
        for (int q = 0; q < 4; ++q) {
          const int i = grp * 4 + q;
          short8 b;
          if (i < WL_NT_V)
            b = wv[i][kt];
          else
            b = *(const short8*)(WL + (((g * WL_NT_LDS + (i - WL_NT_V)) * 8 + kt) * 64 + lane) * 8);
          ac[q] = __builtin_amdgcn_mfma_f32_16x16x32_bf16(a, b, ac[q], 0, 0, 0);
        }
      }
#pragma unroll
      for (int q = 0; q < 4; ++q) {
        const int i = grp * 4 + q;
#pragma unroll
        for (int r = 0; r < 4; ++r)
          TH[(g * 16 + lg * 4 + r) * THSTR + i * 16 + c] = f2bf(__cosf(ac[q][r]));
      }
    }

    // ---- wave-local segmented cumprod + activation (rows of own gate) ----
#pragma unroll
    for (int p = 0; p < 4; ++p) {
      const int row = g * 16 + p * 4 + lg;
      const int s = c;
      bf16_t* rp = TH + row * THSTR + s * 16;
      short8 v0 = *(const short8*)rp;
      short8 v1 = *(const short8*)(rp + 8);
      float vv[16];
#pragma unroll
      for (int j = 0; j < 8; ++j) { vv[j] = bf2f(v0[j]); vv[8 + j] = bf2f(v1[j]); }
      float sp = vv[0];
#pragma unroll
      for (int j = 1; j < 16; ++j) sp *= vv[j];
      float incl = sp;
#pragma unroll
      for (int d = 1; d < 16; d <<= 1) {
        float o = __shfl_up(incl, d, 16);
        if (s >= d) incl *= o;
      }
      float run = __shfl_up(incl, 1, 16);
      if (s == 0) run = 1.f;
      short8 o0, o1;
#pragma unroll
      for (int j = 0; j < 16; ++j) {
        run *= vv[j];
        float u = run * invt;
        float a = (g == 2) ? fast_tanh(u) : fast_sigmoid(u);
        if (j < 8) o0[j] = f2bf(a); else o1[j - 8] = f2bf(a);
      }
      *(short8*)rp = o0;
      *(short8*)(rp + 8) = o1;
    }

    // prefetch next step's theta_x (hidden under B1 + update)
    if (ts + 1 < nsteps) {
      const uint2* tb = thx2 + (((size_t)(ts + 1) * 16 + gg) * 4 + g) * 1024 + lane;
#pragma unroll
      for (int i = 0; i < 16; ++i) tx[i] = tb[i * 64];
    }
    __syncthreads();   // B1: all gates' activations in TH

    // ---- cell update: thread <-> kk; loop b ----
    {
      const int kk = tid;
#pragma unroll
      for (int b = 0; b < 16; ++b) {
        float fv = bf2f(TH[(0 * 16 + b) * THSTR + kk]);
        float iv = bf2f(TH[(1 * 16 + b) * THSTR + kk]);
        float gv = bf2f(TH[(2 * 16 + b) * THSTR + kk]);
        float ov = bf2f(TH[(3 * 16 + b) * THSTR + kk]);
        float cold = C[b * CSTR + kk];
        float cnew = fv * cold + iv * gv;
        C[b * CSTR + kk] = cnew;
        float h = ov * fast_tanh(cnew);
        out[((size_t)t * BATCH + b0 + b) * DHID + kk] = h;
        *(bf16_t*)(Ab + b * 512 + ((kk * 2) ^ ((b & 7) << 4))) = f2bf(h);
        if (t == T_STEPS - 1) {
          out[((size_t)T_STEPS * BATCH + b0 + b) * DHID + kk] = h;
          out[((size_t)T_STEPS * BATCH + BATCH + b0 + b) * DHID + kk] = cnew;
        }
        if (ts == nsteps - 1) {
          hG[(size_t)(b0 + b) * 256 + kk] = f2bf(h);
          cG[(size_t)(b0 + b) * 256 + kk] = cnew;
        }
      }
    }
    __syncthreads();   // B2: A(t+1) complete
  }
}

extern "C" void kernel_launch(void* const* d_in, const int* in_sizes, int n_in,
                              void* d_out, int out_size, void* d_ws, size_t ws_size,
                              hipStream_t stream) {
  (void)in_sizes; (void)n_in; (void)out_size;
  const float* x   = (const float*)d_in[0];
  const float* Wf  = (const float*)d_in[1];
  const float* bf_ = (const float*)d_in[2];
  const float* tf_ = (const float*)d_in[3];
  const float* Wi  = (const float*)d_in[4];
  const float* bi_ = (const float*)d_in[5];
  const float* ti_ = (const float*)d_in[6];
  const float* Wg  = (const float*)d_in[7];
  const float* bg_ = (const float*)d_in[8];
  const float* tg_ = (const float*)d_in[9];
  const float* Wo  = (const float*)d_in[10];
  const float* bo_ = (const float*)d_in[11];
  const float* to_ = (const float*)d_in[12];

  char* ws = (char*)d_ws;
  bf16_t* Whp   = (bf16_t*)(ws + WS_WHP);
  bf16_t* Wxp   = (bf16_t*)(ws + WS_WXP);
  float*  bias  = (float*)(ws + WS_BIAS);
  float*  temps = (float*)(ws + WS_TMP);
  bf16_t* hG    = (bf16_t*)(ws + WS_HG);
  float*  cG    = (float*)(ws + WS_CG);
  bf16_t* thx   = (bf16_t*)(ws + WS_THX);

  // chunk size from available workspace: need 2MB + CH*512KB
  size_t avail = ws_size > (size_t)(2u << 20) ? ws_size - (size_t)(2u << 20) : 0;
  int CH = 2;
  const int cands[8] = {512, 256, 128, 64, 32, 16, 8, 4};
  for (int ci = 0; ci < 8; ++ci)
    if ((size_t)cands[ci] * 512 * 1024 <= avail) { CH = cands[ci]; break; }

  hipLaunchKernelGGL(pack_w, dim3(256), dim3(256), 0, stream,
                     Wf, Wi, Wg, Wo, bf_, bi_, bg_, bo_, tf_, ti_, tg_, to_,
                     Wxp, Whp, bias, temps);

  (void)hipFuncSetAttribute((const void*)qlstm_rec,
                            hipFuncAttributeMaxDynamicSharedMemorySize,
                            LDS_REC);

  for (int c0 = 0; c0 < T_STEPS; c0 += CH) {
    hipLaunchKernelGGL(gemm_thx, dim3(CH * 4), dim3(256), 0, stream,
                       x + (size_t)c0 * BATCH * DIN, Wxp, bias, thx);
    hipLaunchKernelGGL(qlstm_rec, dim3(NWG), dim3(256), LDS_REC, stream,
                       thx, Whp, temps, hG, cG, (float*)d_out, c0, CH);
  }
}

// Round 5
// 2489.172 us; speedup vs baseline: 8.7698x; 2.9407x over previous
//
#include <hip/hip_runtime.h>

#define T_STEPS 512
#define BATCH   256
#define DIN     256
#define DHID    256
#define BBLK    4        // batch rows per WG
#define NWG     64       // BATCH / BBLK
#define NTHREADS 256     // 4 waves, wave = gate

typedef short bf16_t;
typedef __attribute__((ext_vector_type(4))) short short4v;
typedef __attribute__((ext_vector_type(8))) short short8;
typedef __attribute__((ext_vector_type(4))) float f32x4;
typedef unsigned int uint;

// ---- REC LDS layout (bytes) ----
// WL: kt 6,7 of all 16 ntiles x 4 gates: ((g*16+i)*2+k)*1024 + lane*16
#define OFF_WL  0
#define SZ_WL   (4 * 16 * 2 * 64 * 16)          // 131072
#define OFF_A   (OFF_WL + SZ_WL)                // A rows 0..3 + zero row
#define SZ_A    (5 * 512)                       // 2560
#define AZROW   (4 * 512)                       // zero-row byte offset in A
#define OFF_TH  (OFF_A + SZ_A)                  // f32 [16 rows][16 seg][20]
#define THSEG   20
#define THSTR   320                             // floats per row
#define SZ_TH   (16 * THSTR * 4)                // 20480
#define OFF_C   (OFF_TH + SZ_TH)                // f32 [4][256]
#define SZ_C    (4 * 256 * 4)                   // 4096
#define LDS_REC (OFF_C + SZ_C)                  // 158208

// ---- workspace layout (bytes) ----
#define WS_WHP   0u                        // 512 KB Wh packed (B-frag order)
#define WS_WXP   (512u << 10)              // 512 KB Wx packed
#define WS_BIAS  (1u << 20)                // 4 KB
#define WS_TMP   ((1u << 20) + 4096u)      // 16 B
#define WS_HG    ((1u << 20) + 8192u)      // 128 KB h state bf16 [256][256]
#define WS_CG    ((1u << 20) + 8192u + 131072u)  // 256 KB c state f32
#define WS_THX   (2u << 20)                // CH*512 KB theta_x chunk

__device__ inline short f2bf(float f) {
  union { float f; uint u; } v; v.f = f;
  uint r = (v.u + 0x7FFFu + ((v.u >> 16) & 1u)) >> 16;
  return (short)r;
}
__device__ inline float u2f(uint u) {
  union { float f; uint u; } v; v.u = u; return v.f;
}
__device__ inline float frcp(float x) { return __builtin_amdgcn_rcpf(x); }
__device__ inline float fast_sigmoid(float x) { return frcp(1.f + __expf(-x)); }
__device__ inline float fast_tanh(float x) {
  float ax = fabsf(x);
  float e = __expf(2.f * ax);              // inf-safe
  float r = 1.f - 2.f * frcp(e + 1.f);
  return copysignf(r, x);
}

// asm MFMA with B operand pinned in AGPRs (class forced by "a" constraint).
__device__ inline void mfma_ag(f32x4& acc, short8 a, short8 b) {
  asm("v_mfma_f32_16x16x32_bf16 %0, %1, %2, %0"
      : "+v"(acc) : "v"(a), "a"(b));
}

// Pack Wx (k<256) and Wh (k>=256) into MFMA B-frag order.
// frag(nt, kt): elem[((nt*8+kt)*64+lane)*8 + j] = W[n][k],
//   n = nt*16 + (lane&15), k = kbase + kt*32 + (lane>>4)*8 + j.
__global__ __launch_bounds__(256) void pack_w(
    const float* __restrict__ Wf, const float* __restrict__ Wi,
    const float* __restrict__ Wg, const float* __restrict__ Wo,
    const float* __restrict__ bf_, const float* __restrict__ bi_,
    const float* __restrict__ bg_, const float* __restrict__ bo_,
    const float* __restrict__ tf_, const float* __restrict__ ti_,
    const float* __restrict__ tg_, const float* __restrict__ to_,
    bf16_t* __restrict__ Wxp, bf16_t* __restrict__ Whp,
    float* __restrict__ bias, float* __restrict__ temps)
{
  int tid = blockIdx.x * 256 + threadIdx.x;   // 65536 threads
  int half = tid >> 15;                        // 0: Wx, 1: Wh
  int idx = tid & 32767;
  int nt = idx >> 9;                           // 0..63
  int kt = (idx >> 6) & 7;
  int lane = idx & 63;
  int n = nt * 16 + (lane & 15);
  int gate = n >> 8, nrow = n & 255;
  int k = (half ? 256 : 0) + kt * 32 + (lane >> 4) * 8;
  const float* W = gate == 0 ? Wf : gate == 1 ? Wi : gate == 2 ? Wg : Wo;
  const float* src = W + (size_t)nrow * 512 + k;
  short8 d;
#pragma unroll
  for (int j = 0; j < 8; ++j) d[j] = f2bf(src[j]);
  bf16_t* dst = half ? Whp : Wxp;
  *(short8*)(dst + (size_t)idx * 8) = d;

  if (tid < 1024) {
    int g2 = tid >> 8;
    const float* bs = g2 == 0 ? bf_ : g2 == 1 ? bi_ : g2 == 2 ? bg_ : bo_;
    bias[tid] = bs[tid & 255];
  }
  if (tid < 4) {
    const float* ts = tid == 0 ? tf_ : tid == 1 ? ti_ : tid == 2 ? tg_ : to_;
    temps[tid] = ts[0];
  }
}

// theta_x GEMM: thx[trel][gg16][gate][i][lane] (uint2 = 4 bf16, acc r0..r3)
__global__ __launch_bounds__(256, 1) void gemm_thx(
    const float* __restrict__ x,        // chunk slice [CH*256, 256]
    const bf16_t* __restrict__ Wxp,
    const float* __restrict__ bias,
    bf16_t* __restrict__ thx)
{
  __shared__ bf16_t Ax[64 * 256];       // XOR-swizzled, 512 B row stride
  const int tid = threadIdx.x;
  const int wave = tid >> 6, lane = tid & 63;
  const int mb = blockIdx.x * 64;

#pragma unroll
  for (int rep = 0; rep < 16; ++rep) {
    int idx = tid + rep * 256;
    int row = idx >> 6, c4f = (idx & 63) * 4;
    float4 v = *(const float4*)(x + (size_t)(mb + row) * 256 + c4f);
    short4v d;
    d[0] = f2bf(v.x); d[1] = f2bf(v.y); d[2] = f2bf(v.z); d[3] = f2bf(v.w);
    *(short4v*)((char*)Ax + row * 512 + ((c4f * 2) ^ ((row & 7) << 4))) = d;
  }
  __syncthreads();

  short8 af[4][8];
#pragma unroll
  for (int mf = 0; mf < 4; ++mf)
#pragma unroll
    for (int kt = 0; kt < 8; ++kt) {
      int row = mf * 16 + (lane & 15);
      int kb = kt * 64 + (lane >> 4) * 16;
      af[mf][kt] = *(const short8*)((char*)Ax + row * 512 + (kb ^ ((row & 7) << 4)));
    }

  uint2* thx2 = (uint2*)thx;
#pragma unroll 1
  for (int i = 0; i < 16; ++i) {
    short8 wfr[8];
#pragma unroll
    for (int kt = 0; kt < 8; ++kt)
      wfr[kt] = *(const short8*)(Wxp + ((((size_t)(wave * 16 + i)) * 8 + kt) * 64 + lane) * 8);
    float bv = bias[wave * 256 + i * 16 + (lane & 15)];
    f32x4 ac[4];
#pragma unroll
    for (int mf = 0; mf < 4; ++mf) ac[mf] = (f32x4){0.f, 0.f, 0.f, 0.f};
#pragma unroll
    for (int kt = 0; kt < 8; ++kt)
#pragma unroll
      for (int mf = 0; mf < 4; ++mf)
        ac[mf] = __builtin_amdgcn_mfma_f32_16x16x32_bf16(af[mf][kt], wfr[kt], ac[mf], 0, 0, 0);
#pragma unroll
    for (int mf = 0; mf < 4; ++mf) {
      int mrow = mb + mf * 16;
      int trel = mrow >> 8, gg = (mrow >> 4) & 15;
      size_t di = ((((size_t)trel * 16 + gg) * 4 + wave) * 16 + i) * 64 + lane;
      uint2 pk;
      pk.x = (uint)(unsigned short)f2bf(ac[mf][0] + bv) |
             ((uint)(unsigned short)f2bf(ac[mf][1] + bv) << 16);
      pk.y = (uint)(unsigned short)f2bf(ac[mf][2] + bv) |
             ((uint)(unsigned short)f2bf(ac[mf][3] + bv) << 16);
      thx2[di] = pk;
    }
  }
}

// Recurrent kernel: 64 WGs x 256 thr (4 waves, 1/SIMD). Wave = gate.
// Wh per wave: kt1-4 in AGPR (256), kt0,5 in VGPR (128), kt6,7 in LDS.
__global__ __launch_bounds__(256, 1) void qlstm_rec(
    const bf16_t* __restrict__ thx,
    const bf16_t* __restrict__ Whp,
    const float* __restrict__ temps,
    bf16_t* __restrict__ hG, float* __restrict__ cG,
    float* __restrict__ out,
    int t0, int nsteps)
{
  extern __shared__ char smem[];
  bf16_t* WL = (bf16_t*)(smem + OFF_WL);
  char*   Ab = smem + OFF_A;
  float*  TH = (float*)(smem + OFF_TH);
  float*  C  = (float*)(smem + OFF_C);

  const int tid = threadIdx.x;
  const int g = tid >> 6, lane = tid & 63;
  const int lg = lane >> 4, c = lane & 15;
  const int gg4 = blockIdx.x;          // 0..63
  const int b0 = gg4 * BBLK;
  const int gg16 = gg4 >> 2, qsel = gg4 & 3;

  // ---- Wh residency ----
  short8 wa[16][4];                    // -> AGPRs (only "a"-constrained uses)
#pragma unroll
  for (int i = 0; i < 16; ++i)
#pragma unroll
    for (int k = 0; k < 4; ++k)
      wa[i][k] = *(const short8*)(Whp + ((((size_t)(g * 16 + i)) * 8 + (k + 1)) * 64 + lane) * 8);
  short8 wv[16][2];                    // VGPRs: kt 0 and 5
#pragma unroll
  for (int i = 0; i < 16; ++i) {
    wv[i][0] = *(const short8*)(Whp + ((((size_t)(g * 16 + i)) * 8 + 0) * 64 + lane) * 8);
    wv[i][1] = *(const short8*)(Whp + ((((size_t)(g * 16 + i)) * 8 + 5) * 64 + lane) * 8);
  }
#pragma unroll
  for (int i = 0; i < 16; ++i)
#pragma unroll
    for (int k = 0; k < 2; ++k)
      *(short8*)(WL + (((g * 16 + i) * 2 + k) * 64 + lane) * 8) =
          *(const short8*)(Whp + ((((size_t)(g * 16 + i)) * 8 + (6 + k)) * 64 + lane) * 8);

  const float invt = frcp(temps[g]);
  const bool isg = (g == 2);

  // ---- init A (4 rows + zero row) and C ----
  {
    uint2 z = make_uint2(0u, 0u);
    ((uint2*)Ab)[tid] = z;             // 256*8 = 2048 B (rows 0..3)
    if (tid < 64) ((uint2*)(Ab + AZROW))[tid] = z;   // zero row
  }
  __syncthreads();
  {
    int b = tid >> 6, kk4 = (tid & 63) * 4;
    uint2 hv = make_uint2(0u, 0u);
    float4 cv = make_float4(0.f, 0.f, 0.f, 0.f);
    if (t0 != 0) {
      hv = *(const uint2*)(hG + (size_t)(b0 + b) * 256 + kk4);
      cv = *(const float4*)(cG + (size_t)(b0 + b) * 256 + kk4);
    }
    *(uint2*)(Ab + b * 512 + ((kk4 * 2) ^ (b << 4))) = hv;
    *(float4*)(&C[b * 256 + kk4]) = cv;
  }
  __syncthreads();

  const uint2* thxb = (const uint2*)thx;
  uint2 tx[16];
  {
    const uint2* tb = thxb + (((size_t)0 * 16 + gg16) * 4 + g) * 1024 + qsel * 16 + c;
#pragma unroll
    for (int i = 0; i < 16; ++i) tx[i] = tb[i * 64];
  }

#pragma unroll 1
  for (int ts = 0; ts < nsteps; ++ts) {
    const int t = t0 + ts;

    // ---- A-frags: row = c (rows >=4 read the shared zero row) ----
    const int abase = (c < 4) ? c * 512 : AZROW;
    short8 af[8];
#pragma unroll
    for (int kt = 0; kt < 8; ++kt)
      af[kt] = *(const short8*)(Ab + abase + ((kt * 64 + lg * 16) ^ ((c & 7) << 4)));

    // ---- GEMM: theta = theta_x + h @ Wh^T ----
#pragma unroll
    for (int grp = 0; grp < 4; ++grp) {
      f32x4 acc[4];
#pragma unroll
      for (int q = 0; q < 4; ++q) {
        uint lo = tx[grp * 4 + q].x, hi = tx[grp * 4 + q].y;
        acc[q][0] = u2f(lo << 16);
        acc[q][1] = u2f(lo & 0xffff0000u);
        acc[q][2] = u2f(hi << 16);
        acc[q][3] = u2f(hi & 0xffff0000u);
      }
      // kt0 (builtin, VGPR) — compiler guards VALU->MFMA SrcC hazard
#pragma unroll
      for (int q = 0; q < 4; ++q)
        acc[q] = __builtin_amdgcn_mfma_f32_16x16x32_bf16(af[0], wv[grp * 4 + q][0], acc[q], 0, 0, 0);
      // kt1..4 (asm, AGPR) — MAI->MAI chains need no waits
#pragma unroll
      for (int k = 0; k < 4; ++k)
#pragma unroll
        for (int q = 0; q < 4; ++q)
          mfma_ag(acc[q], af[1 + k], wa[grp * 4 + q][k]);
      // kt5 (builtin, VGPR)
#pragma unroll
      for (int q = 0; q < 4; ++q)
        acc[q] = __builtin_amdgcn_mfma_f32_16x16x32_bf16(af[5], wv[grp * 4 + q][1], acc[q], 0, 0, 0);
      // kt6,7 (builtin, LDS) — compiler guards trailing MFMA->VALU hazard
#pragma unroll
      for (int k = 0; k < 2; ++k)
#pragma unroll
        for (int q = 0; q < 4; ++q) {
          short8 b = *(const short8*)(WL + (((g * 16 + grp * 4 + q) * 2 + k) * 64 + lane) * 8);
          acc[q] = __builtin_amdgcn_mfma_f32_16x16x32_bf16(af[6 + k], b, acc[q], 0, 0, 0);
        }
      // store raw theta (f32) for real rows (lg==0 holds D rows 0..3)
      if (lg == 0) {
#pragma unroll
        for (int q = 0; q < 4; ++q)
#pragma unroll
          for (int r = 0; r < 4; ++r)
            TH[(g * 4 + r) * THSTR + (grp * 4 + q) * THSEG + c] = acc[q][r];
      }
    }

    // ---- prefetch next step's theta_x (consumed after B2) ----
    {
      int tsn = (ts + 1 < nsteps) ? ts + 1 : ts;
      const uint2* tb = thxb + (((size_t)tsn * 16 + gg16) * 4 + g) * 1024 + qsel * 16 + c;
#pragma unroll
      for (int i = 0; i < 16; ++i) tx[i] = tb[i * 64];
    }

    // ---- wave-local cos + segmented cumprod + activation ----
    {
      float* rp = TH + (g * 4 + lg) * THSTR + c * THSEG;
      float vv[16];
#pragma unroll
      for (int u = 0; u < 4; ++u) {
        f32x4 v = *(const f32x4*)(rp + u * 4);
        vv[u * 4 + 0] = __cosf(v[0]);
        vv[u * 4 + 1] = __cosf(v[1]);
        vv[u * 4 + 2] = __cosf(v[2]);
        vv[u * 4 + 3] = __cosf(v[3]);
      }
      float sp = vv[0];
#pragma unroll
      for (int j = 1; j < 16; ++j) sp *= vv[j];
      float incl = sp;
#pragma unroll
      for (int d = 1; d < 16; d <<= 1) {
        float o = __shfl_up(incl, d, 16);
        if (c >= d) incl *= o;
      }
      float run = __shfl_up(incl, 1, 16);
      if (c == 0) run = 1.f;
#pragma unroll
      for (int j = 0; j < 16; ++j) {
        run *= vv[j];
        float u = run * invt;
        vv[j] = isg ? fast_tanh(u) : fast_sigmoid(u);
      }
#pragma unroll
      for (int u = 0; u < 4; ++u) {
        f32x4 w;
        w[0] = vv[u * 4 + 0]; w[1] = vv[u * 4 + 1];
        w[2] = vv[u * 4 + 2]; w[3] = vv[u * 4 + 3];
        *(f32x4*)(rp + u * 4) = w;
      }
    }
    __syncthreads();   // B1: all gates' activations in TH

    // ---- cell update: thread <-> kk, 4 batch rows ----
    {
      const int kk = tid;
      const int ko = (kk >> 4) * THSEG + (kk & 15);
#pragma unroll
      for (int b = 0; b < 4; ++b) {
        float fv = TH[(0 * 4 + b) * THSTR + ko];
        float iv = TH[(1 * 4 + b) * THSTR + ko];
        float gv = TH[(2 * 4 + b) * THSTR + ko];
        float ov = TH[(3 * 4 + b) * THSTR + ko];
        float cold = C[b * 256 + kk];
        float cnew = fv * cold + iv * gv;
        C[b * 256 + kk] = cnew;
        float h = ov * fast_tanh(cnew);
        out[((size_t)t * BATCH + b0 + b) * DHID + kk] = h;
        *(bf16_t*)(Ab + b * 512 + ((kk * 2) ^ (b << 4))) = f2bf(h);
        if (t == T_STEPS - 1) {
          out[((size_t)T_STEPS * BATCH + b0 + b) * DHID + kk] = h;
          out[((size_t)T_STEPS * BATCH + BATCH + b0 + b) * DHID + kk] = cnew;
        }
        if (ts == nsteps - 1) {
          hG[(size_t)(b0 + b) * 256 + kk] = f2bf(h);
          cG[(size_t)(b0 + b) * 256 + kk] = cnew;
        }
      }
    }
    __syncthreads();   // B2: A(t+1) complete
  }
}

extern "C" void kernel_launch(void* const* d_in, const int* in_sizes, int n_in,
                              void* d_out, int out_size, void* d_ws, size_t ws_size,
                              hipStream_t stream) {
  (void)in_sizes; (void)n_in; (void)out_size;
  const float* x   = (const float*)d_in[0];
  const float* Wf  = (const float*)d_in[1];
  const float* bf_ = (const float*)d_in[2];
  const float* tf_ = (const float*)d_in[3];
  const float* Wi  = (const float*)d_in[4];
  const float* bi_ = (const float*)d_in[5];
  const float* ti_ = (const float*)d_in[6];
  const float* Wg  = (const float*)d_in[7];
  const float* bg_ = (const float*)d_in[8];
  const float* tg_ = (const float*)d_in[9];
  const float* Wo  = (const float*)d_in[10];
  const float* bo_ = (const float*)d_in[11];
  const float* to_ = (const float*)d_in[12];

  char* ws = (char*)d_ws;
  bf16_t* Whp   = (bf16_t*)(ws + WS_WHP);
  bf16_t* Wxp   = (bf16_t*)(ws + WS_WXP);
  float*  bias  = (float*)(ws + WS_BIAS);
  float*  temps = (float*)(ws + WS_TMP);
  bf16_t* hG    = (bf16_t*)(ws + WS_HG);
  float*  cG    = (float*)(ws + WS_CG);
  bf16_t* thx   = (bf16_t*)(ws + WS_THX);

  size_t avail = ws_size > (size_t)(2u << 20) ? ws_size - (size_t)(2u << 20) : 0;
  int CH = 4;
  const int cands[6] = {128, 64, 32, 16, 8, 4};
  for (int ci = 0; ci < 6; ++ci)
    if ((size_t)cands[ci] * 512 * 1024 <= avail) { CH = cands[ci]; break; }

  hipLaunchKernelGGL(pack_w, dim3(256), dim3(256), 0, stream,
                     Wf, Wi, Wg, Wo, bf_, bi_, bg_, bo_, tf_, ti_, tg_, to_,
                     Wxp, Whp, bias, temps);

  (void)hipFuncSetAttribute((const void*)qlstm_rec,
                            hipFuncAttributeMaxDynamicSharedMemorySize,
                            LDS_REC);

  for (int c0 = 0; c0 < T_STEPS; c0 += CH) {
    hipLaunchKernelGGL(gemm_thx, dim3(CH * 4), dim3(256), 0, stream,
                       x + (size_t)c0 * BATCH * DIN, Wxp, bias, thx);
    hipLaunchKernelGGL(qlstm_rec, dim3(NWG), dim3(256), LDS_REC, stream,
                       thx, Whp, temps, hG, cG, (float*)d_out, c0, CH);
  }
}